// Round 1
// baseline (299.651 us; speedup 1.0000x reference)
//
#include <hip/hip_runtime.h>
#include <hip/hip_bf16.h>
#include <math.h>

// EdgeDistancesPassing: out[e] = exp(-relu(relu((f[src]-f[dst])@W1 + b1)@W2 + b2)) * f[dst]
// Linearity: (f[src]-f[dst])@W1 = P[src]-P[dst] with P = features@W1 (b1 added per-edge).

#define D 64
#define NPB 64  // nodes per block in the projection kernel

// ---------------- Kernel 1: P = features @ W1 (no bias) ----------------
__global__ __launch_bounds__(256) void node_proj_kernel(
    const float* __restrict__ F, const float* __restrict__ W1,
    float* __restrict__ P, int n_nodes)
{
    __shared__ float sW[D * D];    // W1 row-major [k][col], 16 KB
    __shared__ float sF[NPB * D];  // 64 feature rows, 16 KB

    const int tid = threadIdx.x;
    const int base = blockIdx.x * NPB;
    const int nrows = min(NPB, n_nodes - base);

    // Stage W1: 1024 float4 / 256 threads = 4 each (coalesced)
    const float4* W4 = (const float4*)W1;
    float4* sW4 = (float4*)sW;
#pragma unroll
    for (int i = 0; i < 4; ++i) sW4[tid + i * 256] = W4[tid + i * 256];

    // Stage feature rows (coalesced)
    const float4* F4 = (const float4*)(F + (long)base * D);
    float4* sF4 = (float4*)sF;
    const int totalf4 = nrows * (D / 4);
    for (int i = tid; i < totalf4; i += 256) sF4[i] = F4[i];
    __syncthreads();

    const int col = tid & 63;   // output column (stride-1 across the wave)
    const int q = tid >> 6;     // 0..3 — which node subset this wave handles

    float acc[16];
#pragma unroll
    for (int i = 0; i < 16; ++i) acc[i] = 0.f;

    // k-loop outer: W1 value held in register across 16 nodes.
    // sF reads are wave-uniform (broadcast, conflict-free);
    // sW reads are stride-1 (2 lanes/bank => free on gfx950).
    for (int k = 0; k < D; ++k) {
        const float w = sW[k * D + col];
#pragma unroll
        for (int i = 0; i < 16; ++i)
            acc[i] += sF[(q + i * 4) * D + k] * w;
    }

#pragma unroll
    for (int i = 0; i < 16; ++i) {
        const int n = q + i * 4;
        if (n < nrows) P[(long)(base + n) * D + col] = acc[i];
    }
}

// ---------------- Kernel 2: per-edge fused epilogue ----------------
// 16 lanes per edge, float4 per lane (64 floats = one feature row).
__global__ __launch_bounds__(256) void edge_kernel(
    const float* __restrict__ P, const float* __restrict__ F,
    const int* __restrict__ src_idx, const int* __restrict__ dst_idx,
    const float* __restrict__ b1, const float* __restrict__ W2,
    const float* __restrict__ b2v,
    float* __restrict__ out, int n_edges)
{
    const int tid = blockIdx.x * blockDim.x + threadIdx.x;
    const int lane16 = threadIdx.x & 15;
    const int e = tid >> 4;
    if (e >= n_edges) return;

    const float4 b1f = ((const float4*)b1)[lane16];
    const float4 w2f = ((const float4*)W2)[lane16];
    const float b2s = b2v[0];

    const long s = (long)src_idx[e];
    const long d = (long)dst_idx[e];

    const float4 ps = ((const float4*)P)[s * 16 + lane16];
    const float4 pd = ((const float4*)P)[d * 16 + lane16];
    const float4 fd = ((const float4*)F)[d * 16 + lane16];

    // h = relu(P[s] - P[d] + b1)
    float hx = fmaxf(ps.x - pd.x + b1f.x, 0.f);
    float hy = fmaxf(ps.y - pd.y + b1f.y, 0.f);
    float hz = fmaxf(ps.z - pd.z + b1f.z, 0.f);
    float hw = fmaxf(ps.w - pd.w + b1f.w, 0.f);

    // partial dot with W2
    float dot = hx * w2f.x + hy * w2f.y + hz * w2f.z + hw * w2f.w;
    // reduce across the 16-lane group (xor masks 1,2,4,8 stay in-group)
    dot += __shfl_xor(dot, 1);
    dot += __shfl_xor(dot, 2);
    dot += __shfl_xor(dot, 4);
    dot += __shfl_xor(dot, 8);

    const float att = fmaxf(dot + b2s, 0.f);
    const float a = __expf(-att);

    float4 o;
    o.x = a * fd.x; o.y = a * fd.y; o.z = a * fd.z; o.w = a * fd.w;
    ((float4*)out)[(long)e * 16 + lane16] = o;
}

extern "C" void kernel_launch(void* const* d_in, const int* in_sizes, int n_in,
                              void* d_out, int out_size, void* d_ws, size_t ws_size,
                              hipStream_t stream) {
    const float* features = (const float*)d_in[0];
    const int*   src_idx  = (const int*)d_in[1];
    const int*   dst_idx  = (const int*)d_in[2];
    const float* W1       = (const float*)d_in[3];
    const float* b1       = (const float*)d_in[4];
    const float* W2       = (const float*)d_in[5];
    const float* b2       = (const float*)d_in[6];
    float* out = (float*)d_out;

    const int n_nodes = in_sizes[0] / D;
    const int n_edges = in_sizes[1];

    float* P = (float*)d_ws;  // n_nodes * D floats = 12.8 MB

    const int grid1 = (n_nodes + NPB - 1) / NPB;
    node_proj_kernel<<<grid1, 256, 0, stream>>>(features, W1, P, n_nodes);

    const int groups_per_block = 256 / 16;  // 16 edges per block
    const int grid2 = (n_edges + groups_per_block - 1) / groups_per_block;
    edge_kernel<<<grid2, 256, 0, stream>>>(P, features, src_idx, dst_idx,
                                           b1, W2, b2, out, n_edges);
}